// Round 5
// baseline (466.555 us; speedup 1.0000x reference)
//
#include <hip/hip_runtime.h>
#include <hip/hip_bf16.h>

// KAN layer, fully fused: out = silu(x)@sb^T + basis(x) contracted with (ssp*coef) + bias.
// A_aug is NEVER materialized: the GEMM super-iterates over i-blocks of 32 (reordered K),
// computes [silu | 6 cubic B-spline basis] in-register from x, ds_writes 7 f16 k-slices
// into LDS (padded stride 40 f16 -> conflict-free A reads). B side = W_aug (768x5376 f16,
// 8.3 MB, built by prep kernel) staged via global_load_lds. Split-i x2, atomicAdd epilogue.

typedef _Float16 f16;
typedef __attribute__((ext_vector_type(8))) _Float16 f16x8;
typedef __attribute__((ext_vector_type(4))) float f32x4;

#define NTOK 8192
#define DIN 768
#define DOUT 768
#define KAUG 5376  // 7*768
#define BM 128
#define BN 128
#define IB 32      // i-block width
#define ISEG 384   // i per split half
#define NIB 12     // ISEG/IB

#define ASTRIDE 40            // padded f16 row stride (80 B = 5*16B -> bank-conflict-free)
#define ASLICE (128 * ASTRIDE)  // 5120 f16 per slot
#define BSLICE (128 * 32)       // 4096 f16 per slot

#define W_BLOCKS 288   // DOUT*(DIN/8)/256
#define Z_BLOCKS 1536  // NTOK*DOUT/(256*16)

typedef __attribute__((address_space(1))) void gvoid;
typedef __attribute__((address_space(3))) void lvoid;

// ---------------- prep: build W_aug + zero out ----------------
__global__ __launch_bounds__(256) void prep(const float* __restrict__ sb,
                                            const float* __restrict__ ssp,
                                            const float* __restrict__ coef,
                                            f16* __restrict__ Wa,
                                            float* __restrict__ out) {
  const int b = blockIdx.x;
  if (b < W_BLOCKS) {
    const int t = b * 256 + threadIdx.x;  // [0, DOUT*96)
    const int o = t / 96;
    const int i8 = (t - o * 96) * 8;
    const size_t idx = (size_t)o * DIN + i8;

    float bb[8], sp[8], cf[48];
    *(float4*)&bb[0] = ((const float4*)(sb + idx))[0];
    *(float4*)&bb[4] = ((const float4*)(sb + idx))[1];
    *(float4*)&sp[0] = ((const float4*)(ssp + idx))[0];
    *(float4*)&sp[4] = ((const float4*)(ssp + idx))[1];
#pragma unroll
    for (int v = 0; v < 12; ++v) *(float4*)&cf[v * 4] = ((const float4*)(coef + idx * 6))[v];

    f16x8 ch0, chm[6];
#pragma unroll
    for (int e = 0; e < 8; ++e) {
      ch0[e] = (f16)bb[e];
#pragma unroll
      for (int m = 0; m < 6; ++m) chm[m][e] = (f16)(sp[e] * cf[e * 6 + m]);
    }
    const size_t base = (size_t)o * KAUG + i8;
    *(f16x8*)&Wa[base] = ch0;
#pragma unroll
    for (int m = 0; m < 6; ++m) *(f16x8*)&Wa[base + (size_t)(m + 1) * DIN] = chm[m];
  } else {
    const int t = (b - W_BLOCKS) * 256 + threadIdx.x;
    float4* o4 = (float4*)out;
    const float4 z = {0.f, 0.f, 0.f, 0.f};
#pragma unroll
    for (int s = 0; s < 4; ++s) o4[(size_t)t * 4 + s] = z;
  }
}

// ---------------- fused transform + GEMM ----------------
// grid 768 = 8 XCD * 96. 128x128 tile, 4 waves (2x2 of 64x64), split-i x2.
// Per super-iter (i-block of 32): P0 write A ch0..3 + DMA B ch0..3 | P1 mfma ch0..3
// | P2 write A ch4..6 + DMA B ch4..6 | P3 mfma ch4..6.  2 blocks/CU (72 KB LDS).
__global__ __launch_bounds__(256, 2) void kan_fused(const float* __restrict__ x,
                                                    const f16* __restrict__ Wa,
                                                    const float* __restrict__ bias,
                                                    float* __restrict__ out) {
  __shared__ alignas(16) f16 As[4 * ASLICE];  // 40 KB
  __shared__ alignas(16) f16 Bs[4 * BSLICE];  // 32 KB

  const int bid = blockIdx.x;
  const int xcd = bid & 7;
  const int slot = bid >> 3;               // 0..95
  const int mb = ((slot & 7) << 3) + xcd;  // 0..63, all tiles of an mb share one XCD
  const int rest = slot >> 3;              // 0..11
  const int nb = rest % 6;                 // 0..5
  const int ks = rest / 6;                 // 0..1
  const int m0 = mb * BM;
  const int n0 = nb * BN;
  const int ibase = ks * ISEG;

  const int tid = threadIdx.x;
  const int wave = tid >> 6;
  const int lane = tid & 63;
  const int wm = (wave >> 1) * 64;
  const int wn = (wave & 1) * 64;
  const int r = lane & 15;
  const int q = lane >> 4;

  // x tile mapping: each thread owns (row = tid>>1, 16 consecutive i at ih)
  const int xrow = tid >> 1;
  const int ih = (tid & 1) * 16;
  const float* xptr = x + (size_t)(m0 + xrow) * DIN + ibase + ih;
  const int arow_off = xrow * ASTRIDE + ih;  // f16 index inside an A slot

  // B staging chunks: chunk c -> row c>>2, k-quarter c&3
  const int c0 = wave * 64 + lane;
  const int c1 = c0 + 256;
  const f16* gB0 = Wa + (size_t)(n0 + (c0 >> 2)) * KAUG + ibase + (c0 & 3) * 8;
  const f16* gB1 = Wa + (size_t)(n0 + (c1 >> 2)) * KAUG + ibase + (c1 & 3) * 8;
  const int boff = wave * 512;  // f16; HW adds lane*16B

  f32x4 acc[4][4] = {};

  float4 xa[4];
  xa[0] = ((const float4*)xptr)[0];
  xa[1] = ((const float4*)xptr)[1];
  xa[2] = ((const float4*)xptr)[2];
  xa[3] = ((const float4*)xptr)[3];

  for (int it = 0; it < NIB; ++it) {
    // ---- transform: 16 x-values -> 7 channels, weights computed once ----
    float xv[16];
    *(float4*)&xv[0] = xa[0];
    *(float4*)&xv[4] = xa[1];
    *(float4*)&xv[8] = xa[2];
    *(float4*)&xv[12] = xa[3];

    f16x8 chv[7][2];
#pragma unroll
    for (int e = 0; e < 16; ++e) {
      const float v = xv[e];
      const float sil = __fdividef(v, 1.0f + __expf(-v));
      // closed-form uniform cubic B-spline, grid t_g=(g-3)*(2/3)-1
      const float s = (v + 1.0f) * 1.5f + 3.0f;
      const float fi = floorf(s);
      const int i0 = (int)fi;
      const float u = s - fi;
      const float um = 1.0f - u;
      const float u2 = u * u, u3 = u2 * u;
      const float w0 = um * um * um * (1.0f / 6.0f);
      const float w1 = (3.0f * u3 - 6.0f * u2 + 4.0f) * (1.0f / 6.0f);
      const float w2 = (-3.0f * u3 + 3.0f * u2 + 3.0f * u + 1.0f) * (1.0f / 6.0f);
      const float w3 = u3 * (1.0f / 6.0f);
      chv[0][e >> 3][e & 7] = (f16)sil;
#pragma unroll
      for (int m = 0; m < 6; ++m) {
        const int d = m - i0 + 3;
        const float w = (d == 0) ? w0 : (d == 1) ? w1 : (d == 2) ? w2 : (d == 3) ? w3 : 0.0f;
        chv[1 + m][e >> 3][e & 7] = (f16)w;
      }
    }

    // ---- P0: A ch0..3 -> slots 0..3 ; B ch0..3 DMA -> slots 0..3 ----
#pragma unroll
    for (int c = 0; c < 4; ++c) {
      *(f16x8*)&As[c * ASLICE + arow_off] = chv[c][0];
      *(f16x8*)&As[c * ASLICE + arow_off + 8] = chv[c][1];
      const size_t gk = (size_t)c * DIN + it * IB;
      __builtin_amdgcn_global_load_lds((gvoid*)(gB0 + gk), (lvoid*)(&Bs[c * BSLICE + boff]), 16, 0, 0);
      __builtin_amdgcn_global_load_lds((gvoid*)(gB1 + gk), (lvoid*)(&Bs[c * BSLICE + boff + 2048]), 16, 0, 0);
    }
    __syncthreads();

    // ---- P1: prefetch next x; mfma ch0..3 ----
    if (it + 1 < NIB) {
      const float* xn = xptr + (it + 1) * IB;
      xa[0] = ((const float4*)xn)[0];
      xa[1] = ((const float4*)xn)[1];
      xa[2] = ((const float4*)xn)[2];
      xa[3] = ((const float4*)xn)[3];
    }
#pragma unroll
    for (int c = 0; c < 4; ++c) {
      f16x8 af[4], bf[4];
#pragma unroll
      for (int mi = 0; mi < 4; ++mi)
        af[mi] = *(const f16x8*)&As[c * ASLICE + (wm + mi * 16 + r) * ASTRIDE + q * 8];
#pragma unroll
      for (int ni = 0; ni < 4; ++ni)
        bf[ni] = *(const f16x8*)&Bs[c * BSLICE + (wn + ni * 16 + r) * 32 + q * 8];
#pragma unroll
      for (int mi = 0; mi < 4; ++mi)
#pragma unroll
        for (int ni = 0; ni < 4; ++ni)
          acc[mi][ni] = __builtin_amdgcn_mfma_f32_16x16x32_f16(af[mi], bf[ni], acc[mi][ni], 0, 0, 0);
    }
    __syncthreads();

    // ---- P2: A ch4..6 -> slots 0..2 ; B ch4..6 DMA -> slots 0..2 ----
#pragma unroll
    for (int c = 0; c < 3; ++c) {
      *(f16x8*)&As[c * ASLICE + arow_off] = chv[4 + c][0];
      *(f16x8*)&As[c * ASLICE + arow_off + 8] = chv[4 + c][1];
      const size_t gk = (size_t)(4 + c) * DIN + it * IB;
      __builtin_amdgcn_global_load_lds((gvoid*)(gB0 + gk), (lvoid*)(&Bs[c * BSLICE + boff]), 16, 0, 0);
      __builtin_amdgcn_global_load_lds((gvoid*)(gB1 + gk), (lvoid*)(&Bs[c * BSLICE + boff + 2048]), 16, 0, 0);
    }
    __syncthreads();

    // ---- P3: mfma ch4..6 ----
#pragma unroll
    for (int c = 0; c < 3; ++c) {
      f16x8 af[4], bf[4];
#pragma unroll
      for (int mi = 0; mi < 4; ++mi)
        af[mi] = *(const f16x8*)&As[c * ASLICE + (wm + mi * 16 + r) * ASTRIDE + q * 8];
#pragma unroll
      for (int ni = 0; ni < 4; ++ni)
        bf[ni] = *(const f16x8*)&Bs[c * BSLICE + (wn + ni * 16 + r) * 32 + q * 8];
#pragma unroll
      for (int mi = 0; mi < 4; ++mi)
#pragma unroll
        for (int ni = 0; ni < 4; ++ni)
          acc[mi][ni] = __builtin_amdgcn_mfma_f32_16x16x32_f16(af[mi], bf[ni], acc[mi][ni], 0, 0, 0);
    }
    __syncthreads();
  }

  // epilogue: D mapping col = lane&15, row = q*4 + reg; atomic into zeroed out
#pragma unroll
  for (int ni = 0; ni < 4; ++ni) {
    const int gcol = n0 + wn + ni * 16 + r;
    const float badd = (ks == 0) ? bias[gcol] : 0.0f;
#pragma unroll
    for (int mi = 0; mi < 4; ++mi) {
#pragma unroll
      for (int rg = 0; rg < 4; ++rg) {
        const int grow = m0 + wm + mi * 16 + q * 4 + rg;
        atomicAdd(&out[(size_t)grow * DOUT + gcol], acc[mi][ni][rg] + badd);
      }
    }
  }
}

extern "C" void kernel_launch(void* const* d_in, const int* in_sizes, int n_in,
                              void* d_out, int out_size, void* d_ws, size_t ws_size,
                              hipStream_t stream) {
  const float* x = (const float*)d_in[0];           // (4,2048,768)
  const float* coef = (const float*)d_in[1];        // (768,768,6)
  const float* scale_base = (const float*)d_in[2];  // (768,768)
  const float* scale_sp = (const float*)d_in[3];    // (768,768)
  const float* bias = (const float*)d_in[4];        // (768,)
  float* out = (float*)d_out;                       // (8192,768)

  f16* Wa = (f16*)d_ws;  // 768*5376*2 = 8.3 MB

  prep<<<W_BLOCKS + Z_BLOCKS, 256, 0, stream>>>(scale_base, scale_sp, coef, Wa, out);
  kan_fused<<<768, 256, 0, stream>>>(x, Wa, bias, out);
}

// Round 6
// 254.531 us; speedup vs baseline: 1.8330x; 1.8330x over previous
//
#include <hip/hip_runtime.h>
#include <hip/hip_bf16.h>

// KAN layer = one augmented GEMM: out = [silu(x)|basis(x)] @ [sb|ssp*coef]^T + bias.
// A' (8192x5376 f16) and W' (768x5376 f16) are stored FRAG-MAJOR: 16-row x 32-k MFMA
// fragment blocks, element (row,k) at ((rb*168+kt)*64 + lane)*8 + e with
// rb=row/16, kt=k/32, lane=((k>>3)&3)*16 + (row&15), e=k&7.
// GEMM has NO LDS and NO barriers: each wave owns a 64x64 tile, fragment loads are
// single coalesced 16B/lane global loads, ping-pong double-buffered in registers so
// the compiler emits fine-grained vmcnt instead of barrier vmcnt(0) drains.
// Split-K x2, atomicAdd epilogue into out zeroed by prep.

typedef _Float16 f16;
typedef __attribute__((ext_vector_type(8))) _Float16 f16x8;
typedef __attribute__((ext_vector_type(4))) float f32x4;

#define NTOK 8192
#define DIN 768
#define DOUT 768
#define KAUG 5376  // 7*768
#define NKT 168    // KAUG/32
#define KHALF 84   // split-K half in kt units

#define A_BLOCKS 3072  // NTOK*(DIN/8)/256
#define W_BLOCKS 288   // DOUT*(DIN/8)/256
#define Z_BLOCKS 1536  // NTOK*DOUT/(256*16)

// frag-major offset for element block (row16-block rb, kt, lane)
__device__ __forceinline__ size_t fragoff(int rb, int kt, int lane) {
  return (((size_t)rb * NKT + kt) * 64 + lane) * 8;
}

// ---------------- prep: build A' , W' (frag-major) + zero out ----------------
__global__ __launch_bounds__(256) void build_all(const float* __restrict__ x,
                                                 const float* __restrict__ sb,
                                                 const float* __restrict__ ssp,
                                                 const float* __restrict__ coef,
                                                 f16* __restrict__ Aa,
                                                 f16* __restrict__ Wa,
                                                 float* __restrict__ out) {
  const int b = blockIdx.x;
  if (b < A_BLOCKS) {
    // ---- A': thread owns (row, 8 consecutive i), writes 7 channel chunks ----
    const int t = b * 256 + threadIdx.x;  // [0, NTOK*96)
    const int row = t / 96;
    const int i8 = (t - row * 96) * 8;

    const float4* xp = (const float4*)(x + (size_t)row * DIN + i8);
    float4 va = xp[0], vb = xp[1];
    float xv[8] = {va.x, va.y, va.z, va.w, vb.x, vb.y, vb.z, vb.w};

    f16x8 ch[7];
#pragma unroll
    for (int e = 0; e < 8; ++e) {
      const float v = xv[e];
      ch[0][e] = (f16)__fdividef(v, 1.0f + __expf(-v));  // silu
      // closed-form uniform cubic B-spline, grid t_g=(g-3)*(2/3)-1
      const float s = (v + 1.0f) * 1.5f + 3.0f;
      const float fi = floorf(s);
      const int i0 = (int)fi;
      const float u = s - fi;
      const float um = 1.0f - u;
      const float u2 = u * u, u3 = u2 * u;
      const float w0 = um * um * um * (1.0f / 6.0f);
      const float w1 = (3.0f * u3 - 6.0f * u2 + 4.0f) * (1.0f / 6.0f);
      const float w2 = (-3.0f * u3 + 3.0f * u2 + 3.0f * u + 1.0f) * (1.0f / 6.0f);
      const float w3 = u3 * (1.0f / 6.0f);
#pragma unroll
      for (int m = 0; m < 6; ++m) {
        const int d = m - i0 + 3;
        const float w = (d == 0) ? w0 : (d == 1) ? w1 : (d == 2) ? w2 : (d == 3) ? w3 : 0.0f;
        ch[1 + m][e] = (f16)w;
      }
    }

    const int rb = row >> 4;
    const int rl = row & 15;
#pragma unroll
    for (int c = 0; c < 7; ++c) {
      const int k = c * DIN + i8;
      const int kt = k >> 5;
      const int lane = ((k >> 3) & 3) * 16 + rl;
      *(f16x8*)&Aa[fragoff(rb, kt, lane)] = ch[c];
    }
  } else if (b < A_BLOCKS + W_BLOCKS) {
    // ---- W': thread owns (o, 8 consecutive i) ----
    const int t = (b - A_BLOCKS) * 256 + threadIdx.x;  // [0, DOUT*96)
    const int o = t / 96;
    const int i8 = (t - o * 96) * 8;
    const size_t idx = (size_t)o * DIN + i8;

    float bb[8], sp[8], cf[48];
    *(float4*)&bb[0] = ((const float4*)(sb + idx))[0];
    *(float4*)&bb[4] = ((const float4*)(sb + idx))[1];
    *(float4*)&sp[0] = ((const float4*)(ssp + idx))[0];
    *(float4*)&sp[4] = ((const float4*)(ssp + idx))[1];
#pragma unroll
    for (int v = 0; v < 12; ++v) *(float4*)&cf[v * 4] = ((const float4*)(coef + idx * 6))[v];

    f16x8 ch[7];
#pragma unroll
    for (int e = 0; e < 8; ++e) {
      ch[0][e] = (f16)bb[e];
#pragma unroll
      for (int m = 0; m < 6; ++m) ch[1 + m][e] = (f16)(sp[e] * cf[e * 6 + m]);
    }

    const int rb = o >> 4;
    const int rl = o & 15;
#pragma unroll
    for (int c = 0; c < 7; ++c) {
      const int k = c * DIN + i8;
      const int kt = k >> 5;
      const int lane = ((k >> 3) & 3) * 16 + rl;
      *(f16x8*)&Wa[fragoff(rb, kt, lane)] = ch[c];
    }
  } else {
    // ---- zero out for the atomic split-K epilogue ----
    const int t = (b - A_BLOCKS - W_BLOCKS) * 256 + threadIdx.x;
    float4* o4 = (float4*)out;
    const float4 z = {0.f, 0.f, 0.f, 0.f};
#pragma unroll
    for (int s = 0; s < 4; ++s) o4[(size_t)t * 4 + s] = z;
  }
}

// ---------------- register GEMM: no LDS, no barriers ----------------
// 768 blocks = 8 XCD * 96; block = (mb 0..63, nb 0..5, ks 0..1); 4 indep waves,
// wave tile 64x64 (acc 4x4 f32x4). Frag loads are coalesced 1KB/instr from the
// frag-major layouts; register ping-pong double buffer; compiler handles vmcnt.
__global__ __launch_bounds__(256, 3) void kan_rgemm(const f16* __restrict__ A,
                                                    const f16* __restrict__ W,
                                                    const float* __restrict__ bias,
                                                    float* __restrict__ out) {
  const int bid = blockIdx.x;
  const int xcd = bid & 7;
  const int slot = bid >> 3;               // 0..95
  const int mb = ((slot & 7) << 3) + xcd;  // 0..63; all (nb,ks) of an mb share one XCD
  const int rest = slot >> 3;              // 0..11
  const int nb = rest % 6;                 // 0..5
  const int ks = rest / 6;                 // 0..1

  const int tid = threadIdx.x;
  const int wave = tid >> 6;
  const int lane = tid & 63;
  const int k0 = ks * KHALF;

  const int rb_base = mb * 8 + (wave >> 1) * 4;  // 4 row-frag-blocks (64 rows)
  const int cb_base = nb * 8 + (wave & 1) * 4;   // 4 col-frag-blocks (64 cols)

  const f16* pa[4];
  const f16* pb[4];
#pragma unroll
  for (int mi = 0; mi < 4; ++mi) pa[mi] = A + fragoff(rb_base + mi, k0, lane);
#pragma unroll
  for (int ni = 0; ni < 4; ++ni) pb[ni] = W + fragoff(cb_base + ni, k0, lane);

  f32x4 acc[4][4] = {};

  f16x8 a0[4], b0[4], a1[4], b1[4];
#pragma unroll
  for (int mi = 0; mi < 4; ++mi) a0[mi] = *(const f16x8*)(pa[mi]);
#pragma unroll
  for (int ni = 0; ni < 4; ++ni) b0[ni] = *(const f16x8*)(pb[ni]);

  for (int kk = 0; kk < KHALF; kk += 2) {
    // load kt = kk+1 (always in range: KHALF even)
#pragma unroll
    for (int mi = 0; mi < 4; ++mi) a1[mi] = *(const f16x8*)(pa[mi] + (kk + 1) * 512);
#pragma unroll
    for (int ni = 0; ni < 4; ++ni) b1[ni] = *(const f16x8*)(pb[ni] + (kk + 1) * 512);
    // compute kt = kk
#pragma unroll
    for (int mi = 0; mi < 4; ++mi)
#pragma unroll
      for (int ni = 0; ni < 4; ++ni)
        acc[mi][ni] = __builtin_amdgcn_mfma_f32_16x16x32_f16(a0[mi], b0[ni], acc[mi][ni], 0, 0, 0);
    // load kt = kk+2
    if (kk + 2 < KHALF) {
#pragma unroll
      for (int mi = 0; mi < 4; ++mi) a0[mi] = *(const f16x8*)(pa[mi] + (kk + 2) * 512);
#pragma unroll
      for (int ni = 0; ni < 4; ++ni) b0[ni] = *(const f16x8*)(pb[ni] + (kk + 2) * 512);
    }
    // compute kt = kk+1
#pragma unroll
    for (int mi = 0; mi < 4; ++mi)
#pragma unroll
      for (int ni = 0; ni < 4; ++ni)
        acc[mi][ni] = __builtin_amdgcn_mfma_f32_16x16x32_f16(a1[mi], b1[ni], acc[mi][ni], 0, 0, 0);
  }

  // epilogue: D mapping col = lane&15, row = (lane>>4)*4 + reg; atomic into zeroed out
  const int r = lane & 15;
  const int q = lane >> 4;
#pragma unroll
  for (int ni = 0; ni < 4; ++ni) {
    const int gcol = (cb_base + ni) * 16 + r;
    const float badd = (ks == 0) ? bias[gcol] : 0.0f;
#pragma unroll
    for (int mi = 0; mi < 4; ++mi) {
#pragma unroll
      for (int rg = 0; rg < 4; ++rg) {
        const int grow = (rb_base + mi) * 16 + q * 4 + rg;
        atomicAdd(&out[(size_t)grow * DOUT + gcol], acc[mi][ni][rg] + badd);
      }
    }
  }
}

extern "C" void kernel_launch(void* const* d_in, const int* in_sizes, int n_in,
                              void* d_out, int out_size, void* d_ws, size_t ws_size,
                              hipStream_t stream) {
  const float* x = (const float*)d_in[0];           // (4,2048,768)
  const float* coef = (const float*)d_in[1];        // (768,768,6)
  const float* scale_base = (const float*)d_in[2];  // (768,768)
  const float* scale_sp = (const float*)d_in[3];    // (768,768)
  const float* bias = (const float*)d_in[4];        // (768,)
  float* out = (float*)d_out;                       // (8192,768)

  f16* Aa = (f16*)d_ws;                                     // 8192*5376*2 = 88.1 MB
  f16* Wa = (f16*)((char*)d_ws + (size_t)NTOK * KAUG * 2);  // 768*5376*2  = 8.3 MB

  build_all<<<A_BLOCKS + W_BLOCKS + Z_BLOCKS, 256, 0, stream>>>(x, scale_base, scale_sp,
                                                                coef, Aa, Wa, out);
  kan_rgemm<<<768, 256, 0, stream>>>(Aa, Wa, bias, out);
}